// Round 25
// baseline (1061.528 us; speedup 1.0000x reference)
//
#include <hip/hip_runtime.h>

// SNN layer: B=8, S=1024, I=512, H=1024, O=512, T=8
// Verified numerics (R22/R24 PASS, absmax=0): BLIS/AOCL kc=512 emulation:
//   K=512  -> single sequential ascending-k fused-FMA chain
//   K=1024 -> chains [0,512)+[512,1024), delta = ch0 + ch1 (one join add)
//   LIF: mem += c; spike = mem>0.5; fired -> 0.0. Layer2: (mem+delta)+b2.
// R25 perf: BK=32 (half the barriers) + register-prefetch double buffering
// (tile it+1 loads issue under tile it compute). Same per-output math.
static constexpr int B_ = 8, S_ = 1024, I_ = 512, H_ = 1024, O_ = 512, T_ = 8;
static constexpr int M_ = B_ * S_;
static constexpr float TH = 0.5f;

// ---------------------------------------------------------------------------
// K1: inp_cur = dot(x, w1^T) + b1 (full-K single chain) -> 8-step LIF ->
// bit-packed spikes. 128x64 tile, 256 threads, 8x4/thread, BK=32, 16 iters.
// ---------------------------------------------------------------------------
__global__ __launch_bounds__(256) void k1(const float* __restrict__ X,
                                          const float* __restrict__ W1,
                                          const float* __restrict__ B1,
                                          unsigned char* __restrict__ SPB) {
  __shared__ float As[32][132];   // 16.9 KB
  __shared__ float Bs[32][68];    //  8.7 KB
  const int tid = threadIdx.x;
  const int tx = tid & 15, ty = tid >> 4;
  const int rowBase = blockIdx.x * 128, colBase = blockIdx.y * 64;
  const int rr = tid >> 3, kq = (tid & 7) << 2;  // staging coords (f = tid+l*256)

  float acc[8][4];
#pragma unroll
  for (int i = 0; i < 8; ++i)
#pragma unroll
    for (int j = 0; j < 4; ++j) acc[i][j] = 0.f;

  float4 pa[4], pb[2];
#define K1_LOAD(IT)                                                            \
  {                                                                            \
    _Pragma("unroll")                                                          \
    for (int l = 0; l < 4; ++l)                                                \
      pa[l] = *(const float4*)&X[(size_t)(rowBase + rr + l * 32) * I_ +        \
                                 (IT) * 32 + kq];                              \
    _Pragma("unroll")                                                          \
    for (int l = 0; l < 2; ++l)                                                \
      pb[l] = *(const float4*)&W1[(size_t)(colBase + rr + l * 32) * I_ +       \
                                  (IT) * 32 + kq];                             \
  }

  K1_LOAD(0);
  for (int it = 0; it < 16; ++it) {
#pragma unroll
    for (int l = 0; l < 4; ++l) {
      As[kq + 0][rr + l * 32] = pa[l].x; As[kq + 1][rr + l * 32] = pa[l].y;
      As[kq + 2][rr + l * 32] = pa[l].z; As[kq + 3][rr + l * 32] = pa[l].w;
    }
#pragma unroll
    for (int l = 0; l < 2; ++l) {
      Bs[kq + 0][rr + l * 32] = pb[l].x; Bs[kq + 1][rr + l * 32] = pb[l].y;
      Bs[kq + 2][rr + l * 32] = pb[l].z; Bs[kq + 3][rr + l * 32] = pb[l].w;
    }
    __syncthreads();
    if (it + 1 < 16) K1_LOAD(it + 1);   // latency hides under compute below
#pragma unroll
    for (int k = 0; k < 32; ++k) {
      float a[8], b[4];
      *(float4*)&a[0] = *(const float4*)&As[k][ty * 8];
      *(float4*)&a[4] = *(const float4*)&As[k][ty * 8 + 4];
      *(float4*)&b[0] = *(const float4*)&Bs[k][tx * 4];
#pragma unroll
      for (int i = 0; i < 8; ++i)
#pragma unroll
        for (int j = 0; j < 4; ++j) acc[i][j] = fmaf(a[i], b[j], acc[i][j]);
    }
    __syncthreads();
  }
#undef K1_LOAD

#pragma unroll
  for (int i = 0; i < 8; ++i) {
    int row = rowBase + ty * 8 + i;
    unsigned char by[4];
#pragma unroll
    for (int j = 0; j < 4; ++j) {
      int col = colBase + tx * 4 + j;
      float c = acc[i][j] + B1[col];  // single chain + b1
      float m = 0.f;
      unsigned bits = 0;
#pragma unroll
      for (int t = 0; t < 8; ++t) {
        m = m + c;
        bool s = m > TH;
        bits |= (s ? 1u : 0u) << t;
        m = s ? 0.f : m;
      }
      by[j] = (unsigned char)bits;
    }
    uchar4 pk; pk.x = by[0]; pk.y = by[1]; pk.z = by[2]; pk.w = by[3];
    *(uchar4*)&SPB[(size_t)row * H_ + colBase + tx * 4] = pk;
  }
}

// ---------------------------------------------------------------------------
// K2 (per step t): delta = dot(spike_t, w2^T), two independent chains
// processed CONCURRENTLY (cur0: k<512, cur1: k>=512), delta = cur0 + cur1;
// mm = (mem_prev + delta) + b2; spikes -> out slice t; next mem stashed in
// out slice t+1. 64x64 tile, 4x4/thread, BK=32, 16 iters.
// ---------------------------------------------------------------------------
__global__ __launch_bounds__(256) void k2(const unsigned char* __restrict__ SP,
                                          const float* __restrict__ W2,
                                          const float* __restrict__ B2,
                                          float* __restrict__ out, int t) {
  __shared__ float As0[32][68];
  __shared__ float As1[32][68];
  __shared__ float Bs0[32][68];
  __shared__ float Bs1[32][68];   // 4 x 8.7 KB = 34.8 KB
  const int tid = threadIdx.x;
  const int tx = tid & 15, ty = tid >> 4;
  const int rowBase = blockIdx.x * 64, colBase = blockIdx.y * 64;
  const int rr = tid >> 3, bq = (tid & 7) << 2;  // staging: f = tid+l*256

  float cur0[4][4], cur1[4][4];
#pragma unroll
  for (int i = 0; i < 4; ++i)
#pragma unroll
    for (int j = 0; j < 4; ++j) { cur0[i][j] = 0.f; cur1[i][j] = 0.f; }

  unsigned pu0[2], pu1[2];
  float4 pb0[2], pb1[2];
#define K2_LOAD(IT)                                                            \
  {                                                                            \
    _Pragma("unroll")                                                          \
    for (int l = 0; l < 2; ++l) {                                              \
      const size_t rowOff = (size_t)(rowBase + rr + l * 32) * H_;              \
      pu0[l] = *(const unsigned*)&SP[rowOff + (IT) * 32 + bq];                 \
      pu1[l] = *(const unsigned*)&SP[rowOff + 512 + (IT) * 32 + bq];           \
      const size_t colOff = (size_t)(colBase + rr + l * 32) * H_;              \
      pb0[l] = *(const float4*)&W2[colOff + (IT) * 32 + bq];                   \
      pb1[l] = *(const float4*)&W2[colOff + 512 + (IT) * 32 + bq];             \
    }                                                                          \
  }

  K2_LOAD(0);
  for (int it = 0; it < 16; ++it) {
#pragma unroll
    for (int l = 0; l < 2; ++l) {
      const int rl = rr + l * 32;
#pragma unroll
      for (int c = 0; c < 4; ++c) {
        As0[bq + c][rl] = (float)((pu0[l] >> (8 * c + t)) & 1u);
        As1[bq + c][rl] = (float)((pu1[l] >> (8 * c + t)) & 1u);
      }
      Bs0[bq + 0][rl] = pb0[l].x; Bs0[bq + 1][rl] = pb0[l].y;
      Bs0[bq + 2][rl] = pb0[l].z; Bs0[bq + 3][rl] = pb0[l].w;
      Bs1[bq + 0][rl] = pb1[l].x; Bs1[bq + 1][rl] = pb1[l].y;
      Bs1[bq + 2][rl] = pb1[l].z; Bs1[bq + 3][rl] = pb1[l].w;
    }
    __syncthreads();
    if (it + 1 < 16) K2_LOAD(it + 1);   // latency hides under compute below
#pragma unroll
    for (int k = 0; k < 32; ++k) {
      float a0[4], b0[4], a1[4], b1v[4];
      *(float4*)&a0[0] = *(const float4*)&As0[k][ty * 4];
      *(float4*)&b0[0] = *(const float4*)&Bs0[k][tx * 4];
      *(float4*)&a1[0] = *(const float4*)&As1[k][ty * 4];
      *(float4*)&b1v[0] = *(const float4*)&Bs1[k][tx * 4];
#pragma unroll
      for (int i = 0; i < 4; ++i)
#pragma unroll
        for (int j = 0; j < 4; ++j) {
          cur0[i][j] = fmaf(a0[i], b0[j], cur0[i][j]);
          cur1[i][j] = fmaf(a1[i], b1v[j], cur1[i][j]);
        }
    }
    __syncthreads();
  }
#undef K2_LOAD

  const int col0 = colBase + tx * 4;
  float4 b2v = *(const float4*)&B2[col0];
#pragma unroll
  for (int i = 0; i < 4; ++i) {
    int row = rowBase + ty * 4 + i;
    int bb = row >> 10;          // row / S_
    int ss = row & (S_ - 1);
    size_t slot_t = (((size_t)bb * T_ + t) * S_ + ss) * O_ + col0;
    float4 mp;
    if (t == 0) mp = make_float4(0.f, 0.f, 0.f, 0.f);
    else mp = *(const float4*)&out[slot_t];  // state stashed by step t-1
    float d[4], mm[4];
#pragma unroll
    for (int j = 0; j < 4; ++j)
      d[j] = cur0[i][j] + cur1[i][j];        // ch0 + ch1 (single join add)
    mm[0] = (mp.x + d[0]) + b2v.x;           // (mem2 + delta) + b2
    mm[1] = (mp.y + d[1]) + b2v.y;
    mm[2] = (mp.z + d[2]) + b2v.z;
    mm[3] = (mp.w + d[3]) + b2v.w;
    float4 sp, mn;
    sp.x = (mm[0] > TH) ? 1.f : 0.f;  mn.x = (mm[0] > TH) ? 0.f : mm[0];
    sp.y = (mm[1] > TH) ? 1.f : 0.f;  mn.y = (mm[1] > TH) ? 0.f : mm[1];
    sp.z = (mm[2] > TH) ? 1.f : 0.f;  mn.z = (mm[2] > TH) ? 0.f : mm[2];
    sp.w = (mm[3] > TH) ? 1.f : 0.f;  mn.w = (mm[3] > TH) ? 0.f : mm[3];
    *(float4*)&out[slot_t] = sp;      // final spikes for step t
    if (t < T_ - 1) {
      size_t slot_n = (((size_t)bb * T_ + (t + 1)) * S_ + ss) * O_ + col0;
      *(float4*)&out[slot_n] = mn;    // stash state; overwritten at t+1
    }
  }
}

extern "C" void kernel_launch(void* const* d_in, const int* in_sizes, int n_in,
                              void* d_out, int out_size, void* d_ws, size_t ws_size,
                              hipStream_t stream) {
  const float* x  = (const float*)d_in[0];   // (B,S,I)
  const float* w1 = (const float*)d_in[1];   // (H,I)
  const float* b1 = (const float*)d_in[2];   // (H)
  const float* w2 = (const float*)d_in[3];   // (O,H)
  const float* b2 = (const float*)d_in[4];   // (O)
  float* out = (float*)d_out;                // (B,T,S,O) f32

  unsigned char* spikeB = (unsigned char*)d_ws;  // M*H bytes = 8.4 MB

  k1<<<dim3(M_ / 128, H_ / 64), 256, 0, stream>>>(x, w1, b1, spikeB);
  for (int t = 0; t < T_; ++t)
    k2<<<dim3(M_ / 64, O_ / 64), 256, 0, stream>>>(spikeB, w2, b2, out, t);
}

// Round 26
// 967.632 us; speedup vs baseline: 1.0970x; 1.0970x over previous
//
#include <hip/hip_runtime.h>

// SNN layer: B=8, S=1024, I=512, H=1024, O=512, T=8
// Verified numerics (R22/R24 PASS, absmax=0): BLIS/AOCL kc=512 emulation:
//   K=512  -> single sequential ascending-k fused-FMA chain
//   K=1024 -> chains [0,512)+[512,1024), delta = ch0 + ch1 (one join add)
//   LIF: mem += c; spike = mem>0.5; fired -> 0.0. Layer2: (mem+delta)+b2.
// R26: R24 structure (983us best: BK=16, k1 128x64/8x4, k2 64x64/4x4 dual-
// chunk) + register-prefetch double buffer (occupancy-neutral: no LDS growth).
static constexpr int B_ = 8, S_ = 1024, I_ = 512, H_ = 1024, O_ = 512, T_ = 8;
static constexpr int M_ = B_ * S_;
static constexpr float TH = 0.5f;

// ---------------------------------------------------------------------------
// K1: inp_cur = dot(x, w1^T) + b1 (full-K single chain) -> 8-step LIF ->
// bit-packed spikes. 128x64 tile, 256 threads, 8x4/thread, BK=16, 32 iters.
// ---------------------------------------------------------------------------
__global__ __launch_bounds__(256) void k1(const float* __restrict__ X,
                                          const float* __restrict__ W1,
                                          const float* __restrict__ B1,
                                          unsigned char* __restrict__ SPB) {
  __shared__ float As[16][132];   // 8.45 KB
  __shared__ float Bs[16][68];    // 4.35 KB
  const int tid = threadIdx.x;
  const int tx = tid & 15, ty = tid >> 4;
  const int rowBase = blockIdx.x * 128, colBase = blockIdx.y * 64;
  const int rrA = tid >> 2, kqA = (tid & 3) << 2;   // A staging (2 chunks of 64 rows)
  const int rrB = tid >> 2, kqB = (tid & 3) << 2;   // B staging (64 rows)

  float acc[8][4];
#pragma unroll
  for (int i = 0; i < 8; ++i)
#pragma unroll
    for (int j = 0; j < 4; ++j) acc[i][j] = 0.f;

  float4 pa0, pa1, pb;
#define K1_LOAD(IT)                                                            \
  {                                                                            \
    pa0 = *(const float4*)&X[(size_t)(rowBase + rrA) * I_ + (IT) * 16 + kqA];  \
    pa1 = *(const float4*)&X[(size_t)(rowBase + 64 + rrA) * I_ + (IT) * 16 + kqA]; \
    pb  = *(const float4*)&W1[(size_t)(colBase + rrB) * I_ + (IT) * 16 + kqB]; \
  }

  K1_LOAD(0);
  for (int it = 0; it < 32; ++it) {
    As[kqA + 0][rrA] = pa0.x; As[kqA + 1][rrA] = pa0.y;
    As[kqA + 2][rrA] = pa0.z; As[kqA + 3][rrA] = pa0.w;
    As[kqA + 0][64 + rrA] = pa1.x; As[kqA + 1][64 + rrA] = pa1.y;
    As[kqA + 2][64 + rrA] = pa1.z; As[kqA + 3][64 + rrA] = pa1.w;
    Bs[kqB + 0][rrB] = pb.x; Bs[kqB + 1][rrB] = pb.y;
    Bs[kqB + 2][rrB] = pb.z; Bs[kqB + 3][rrB] = pb.w;
    __syncthreads();
    if (it + 1 < 32) K1_LOAD(it + 1);   // hide global latency under compute
#pragma unroll
    for (int k = 0; k < 16; ++k) {
      float a[8], b[4];
      *(float4*)&a[0] = *(const float4*)&As[k][ty * 8];
      *(float4*)&a[4] = *(const float4*)&As[k][ty * 8 + 4];
      *(float4*)&b[0] = *(const float4*)&Bs[k][tx * 4];
#pragma unroll
      for (int i = 0; i < 8; ++i)
#pragma unroll
        for (int j = 0; j < 4; ++j) acc[i][j] = fmaf(a[i], b[j], acc[i][j]);
    }
    __syncthreads();
  }
#undef K1_LOAD

#pragma unroll
  for (int i = 0; i < 8; ++i) {
    int row = rowBase + ty * 8 + i;
    unsigned char by[4];
#pragma unroll
    for (int j = 0; j < 4; ++j) {
      int col = colBase + tx * 4 + j;
      float c = acc[i][j] + B1[col];  // single chain + b1
      float m = 0.f;
      unsigned bits = 0;
#pragma unroll
      for (int t = 0; t < 8; ++t) {
        m = m + c;
        bool s = m > TH;
        bits |= (s ? 1u : 0u) << t;
        m = s ? 0.f : m;
      }
      by[j] = (unsigned char)bits;
    }
    uchar4 pk; pk.x = by[0]; pk.y = by[1]; pk.z = by[2]; pk.w = by[3];
    *(uchar4*)&SPB[(size_t)row * H_ + colBase + tx * 4] = pk;
  }
}

// ---------------------------------------------------------------------------
// K2 (per step t): delta = dot(spike_t, w2^T), two independent chains
// processed CONCURRENTLY (cur0: k<512, cur1: k>=512), delta = cur0 + cur1;
// mm = (mem_prev + delta) + b2; spikes -> out slice t; next mem stashed in
// out slice t+1. 64x64 tile, 4x4/thread, BK=16, 32 iters.
// ---------------------------------------------------------------------------
__global__ __launch_bounds__(256) void k2(const unsigned char* __restrict__ SP,
                                          const float* __restrict__ W2,
                                          const float* __restrict__ B2,
                                          float* __restrict__ out, int t) {
  __shared__ float As0[16][68];
  __shared__ float As1[16][68];
  __shared__ float Bs0[16][68];
  __shared__ float Bs1[16][68];   // 17.4 KB total
  const int tid = threadIdx.x;
  const int tx = tid & 15, ty = tid >> 4;
  const int rowBase = blockIdx.x * 64, colBase = blockIdx.y * 64;
  const int rr = tid >> 2, bq = (tid & 3) << 2;

  float cur0[4][4], cur1[4][4];
#pragma unroll
  for (int i = 0; i < 4; ++i)
#pragma unroll
    for (int j = 0; j < 4; ++j) { cur0[i][j] = 0.f; cur1[i][j] = 0.f; }

  unsigned pu0, pu1;
  float4 pb0, pb1;
#define K2_LOAD(IT)                                                            \
  {                                                                            \
    const size_t rowOff = (size_t)(rowBase + rr) * H_;                         \
    pu0 = *(const unsigned*)&SP[rowOff + (IT) * 16 + bq];                      \
    pu1 = *(const unsigned*)&SP[rowOff + 512 + (IT) * 16 + bq];                \
    const size_t colOff = (size_t)(colBase + rr) * H_;                         \
    pb0 = *(const float4*)&W2[colOff + (IT) * 16 + bq];                        \
    pb1 = *(const float4*)&W2[colOff + 512 + (IT) * 16 + bq];                  \
  }

  K2_LOAD(0);
  for (int it = 0; it < 32; ++it) {
#pragma unroll
    for (int c = 0; c < 4; ++c) {
      As0[bq + c][rr] = (float)((pu0 >> (8 * c + t)) & 1u);
      As1[bq + c][rr] = (float)((pu1 >> (8 * c + t)) & 1u);
    }
    Bs0[bq + 0][rr] = pb0.x; Bs0[bq + 1][rr] = pb0.y;
    Bs0[bq + 2][rr] = pb0.z; Bs0[bq + 3][rr] = pb0.w;
    Bs1[bq + 0][rr] = pb1.x; Bs1[bq + 1][rr] = pb1.y;
    Bs1[bq + 2][rr] = pb1.z; Bs1[bq + 3][rr] = pb1.w;
    __syncthreads();
    if (it + 1 < 32) K2_LOAD(it + 1);   // hide global latency under compute
#pragma unroll
    for (int k = 0; k < 16; ++k) {
      float a0[4], b0[4], a1[4], b1v[4];
      *(float4*)&a0[0] = *(const float4*)&As0[k][ty * 4];
      *(float4*)&b0[0] = *(const float4*)&Bs0[k][tx * 4];
      *(float4*)&a1[0] = *(const float4*)&As1[k][ty * 4];
      *(float4*)&b1v[0] = *(const float4*)&Bs1[k][tx * 4];
#pragma unroll
      for (int i = 0; i < 4; ++i)
#pragma unroll
        for (int j = 0; j < 4; ++j) {
          cur0[i][j] = fmaf(a0[i], b0[j], cur0[i][j]);
          cur1[i][j] = fmaf(a1[i], b1v[j], cur1[i][j]);
        }
    }
    __syncthreads();
  }
#undef K2_LOAD

  const int col0 = colBase + tx * 4;
  float4 b2v = *(const float4*)&B2[col0];
#pragma unroll
  for (int i = 0; i < 4; ++i) {
    int row = rowBase + ty * 4 + i;
    int bb = row >> 10;          // row / S_
    int ss = row & (S_ - 1);
    size_t slot_t = (((size_t)bb * T_ + t) * S_ + ss) * O_ + col0;
    float4 mp;
    if (t == 0) mp = make_float4(0.f, 0.f, 0.f, 0.f);
    else mp = *(const float4*)&out[slot_t];  // state stashed by step t-1
    float d[4], mm[4];
#pragma unroll
    for (int j = 0; j < 4; ++j)
      d[j] = cur0[i][j] + cur1[i][j];        // ch0 + ch1 (single join add)
    mm[0] = (mp.x + d[0]) + b2v.x;           // (mem2 + delta) + b2
    mm[1] = (mp.y + d[1]) + b2v.y;
    mm[2] = (mp.z + d[2]) + b2v.z;
    mm[3] = (mp.w + d[3]) + b2v.w;
    float4 sp, mn;
    sp.x = (mm[0] > TH) ? 1.f : 0.f;  mn.x = (mm[0] > TH) ? 0.f : mm[0];
    sp.y = (mm[1] > TH) ? 1.f : 0.f;  mn.y = (mm[1] > TH) ? 0.f : mm[1];
    sp.z = (mm[2] > TH) ? 1.f : 0.f;  mn.z = (mm[2] > TH) ? 0.f : mm[2];
    sp.w = (mm[3] > TH) ? 1.f : 0.f;  mn.w = (mm[3] > TH) ? 0.f : mm[3];
    *(float4*)&out[slot_t] = sp;      // final spikes for step t
    if (t < T_ - 1) {
      size_t slot_n = (((size_t)bb * T_ + (t + 1)) * S_ + ss) * O_ + col0;
      *(float4*)&out[slot_n] = mn;    // stash state; overwritten at t+1
    }
  }
}

extern "C" void kernel_launch(void* const* d_in, const int* in_sizes, int n_in,
                              void* d_out, int out_size, void* d_ws, size_t ws_size,
                              hipStream_t stream) {
  const float* x  = (const float*)d_in[0];   // (B,S,I)
  const float* w1 = (const float*)d_in[1];   // (H,I)
  const float* b1 = (const float*)d_in[2];   // (H)
  const float* w2 = (const float*)d_in[3];   // (O,H)
  const float* b2 = (const float*)d_in[4];   // (O)
  float* out = (float*)d_out;                // (B,T,S,O) f32

  unsigned char* spikeB = (unsigned char*)d_ws;  // M*H bytes = 8.4 MB

  k1<<<dim3(M_ / 128, H_ / 64), 256, 0, stream>>>(x, w1, b1, spikeB);
  for (int t = 0; t < T_; ++t)
    k2<<<dim3(M_ / 64, O_ / 64), 256, 0, stream>>>(spikeB, w2, b2, out, t);
}

// Round 27
// 842.474 us; speedup vs baseline: 1.2600x; 1.1486x over previous
//
#include <hip/hip_runtime.h>

// SNN layer: B=8, S=1024, I=512, H=1024, O=512, T=8
// Verified numerics (R22/R24/R26 PASS, absmax=0): BLIS/AOCL kc=512 emulation:
//   K=512  -> single sequential ascending-k fused-FMA chain
//   K=1024 -> chains [0,512)+[512,1024), delta = ch0 + ch1 (one join add)
//   LIF: mem += c; spike = mem>0.5; fired -> 0.0. Layer2: (mem+delta)+b2.
// R27: k2 fuses 4 timesteps per launch (8 -> 2 launches): W2/spike staging,
// barriers, and mem2 round-trips amortized 4x. mem2 recurrence for the 4
// fused t's runs in registers; state crosses launches via out slice 4.
static constexpr int B_ = 8, S_ = 1024, I_ = 512, H_ = 1024, O_ = 512, T_ = 8;
static constexpr int M_ = B_ * S_;
static constexpr float TH = 0.5f;

// ---------------------------------------------------------------------------
// K1 (unchanged R26): inp_cur = dot(x, w1^T) + b1 (full-K single chain) ->
// 8-step LIF -> bit-packed spikes. 128x64 tile, 8x4/thread, BK=16.
// ---------------------------------------------------------------------------
__global__ __launch_bounds__(256) void k1(const float* __restrict__ X,
                                          const float* __restrict__ W1,
                                          const float* __restrict__ B1,
                                          unsigned char* __restrict__ SPB) {
  __shared__ float As[16][132];
  __shared__ float Bs[16][68];
  const int tid = threadIdx.x;
  const int tx = tid & 15, ty = tid >> 4;
  const int rowBase = blockIdx.x * 128, colBase = blockIdx.y * 64;
  const int rrA = tid >> 2, kqA = (tid & 3) << 2;

  float acc[8][4];
#pragma unroll
  for (int i = 0; i < 8; ++i)
#pragma unroll
    for (int j = 0; j < 4; ++j) acc[i][j] = 0.f;

  float4 pa0, pa1, pb;
#define K1_LOAD(IT)                                                            \
  {                                                                            \
    pa0 = *(const float4*)&X[(size_t)(rowBase + rrA) * I_ + (IT) * 16 + kqA];  \
    pa1 = *(const float4*)&X[(size_t)(rowBase + 64 + rrA) * I_ + (IT) * 16 + kqA]; \
    pb  = *(const float4*)&W1[(size_t)(colBase + rrA) * I_ + (IT) * 16 + kqA]; \
  }

  K1_LOAD(0);
  for (int it = 0; it < 32; ++it) {
    As[kqA + 0][rrA] = pa0.x; As[kqA + 1][rrA] = pa0.y;
    As[kqA + 2][rrA] = pa0.z; As[kqA + 3][rrA] = pa0.w;
    As[kqA + 0][64 + rrA] = pa1.x; As[kqA + 1][64 + rrA] = pa1.y;
    As[kqA + 2][64 + rrA] = pa1.z; As[kqA + 3][64 + rrA] = pa1.w;
    Bs[kqA + 0][rrA] = pb.x; Bs[kqA + 1][rrA] = pb.y;
    Bs[kqA + 2][rrA] = pb.z; Bs[kqA + 3][rrA] = pb.w;
    __syncthreads();
    if (it + 1 < 32) K1_LOAD(it + 1);
#pragma unroll
    for (int k = 0; k < 16; ++k) {
      float a[8], b[4];
      *(float4*)&a[0] = *(const float4*)&As[k][ty * 8];
      *(float4*)&a[4] = *(const float4*)&As[k][ty * 8 + 4];
      *(float4*)&b[0] = *(const float4*)&Bs[k][tx * 4];
#pragma unroll
      for (int i = 0; i < 8; ++i)
#pragma unroll
        for (int j = 0; j < 4; ++j) acc[i][j] = fmaf(a[i], b[j], acc[i][j]);
    }
    __syncthreads();
  }
#undef K1_LOAD

#pragma unroll
  for (int i = 0; i < 8; ++i) {
    int row = rowBase + ty * 8 + i;
    unsigned char by[4];
#pragma unroll
    for (int j = 0; j < 4; ++j) {
      int col = colBase + tx * 4 + j;
      float c = acc[i][j] + B1[col];
      float m = 0.f;
      unsigned bits = 0;
#pragma unroll
      for (int t = 0; t < 8; ++t) {
        m = m + c;
        bool s = m > TH;
        bits |= (s ? 1u : 0u) << t;
        m = s ? 0.f : m;
      }
      by[j] = (unsigned char)bits;
    }
    uchar4 pk; pk.x = by[0]; pk.y = by[1]; pk.z = by[2]; pk.w = by[3];
    *(uchar4*)&SPB[(size_t)row * H_ + colBase + tx * 4] = pk;
  }
}

// ---------------------------------------------------------------------------
// K2F: 4 timesteps fused (tg=0: t=0..3, tg=1: t=4..7).
// Block 32 rows x 64 cols, 256 threads, micro 2x4, BK=16 (64 iters).
// As[k][row*4+t] holds spike floats for the 4 fused t's; Bs[k][col] = W2.
// Chunk join at it==32 (k=512): tot += cur (tot starts 0 -> exact).
// Epilogue: in-register mem2 recurrence over the 4 t's; state read/stash in
// out slice 4 at the group boundary.
// ---------------------------------------------------------------------------
__global__ __launch_bounds__(256) void k2f(const unsigned char* __restrict__ SP,
                                           const float* __restrict__ W2,
                                           const float* __restrict__ B2,
                                           float* __restrict__ out, int tg) {
  __shared__ float As[16][132];   // [k][row*4 + tt], 32 rows, pad +4
  __shared__ float Bs[16][68];    // [k][col], 64 cols
  const int tid = threadIdx.x;
  const int tx = tid & 15, ty = tid >> 4;
  const int rowBase = blockIdx.x * 32, colBase = blockIdx.y * 64;
  const int sr = tid >> 3;             // 0..31 (A staging row)
  const int sk = (tid & 7) << 1;       // 0,2,..,14 (A staging k-pair)
  const int bc = tid >> 2;             // 0..63 (B staging col)
  const int bk = (tid & 3) << 2;       // 0,4,8,12 (B staging k-quad)
  const int tb = tg * 4;               // bit base for this t-group

  float tot[2][4][4], cur[2][4][4];    // [i(row)][j(col)][tt]
#pragma unroll
  for (int i = 0; i < 2; ++i)
#pragma unroll
    for (int j = 0; j < 4; ++j)
#pragma unroll
      for (int tt = 0; tt < 4; ++tt) { tot[i][j][tt] = 0.f; cur[i][j][tt] = 0.f; }

  unsigned pu;
  float4 pb;
#define K2_LOAD(IT)                                                            \
  {                                                                            \
    pu = *(const unsigned short*)&SP[(size_t)(rowBase + sr) * H_ + (IT) * 16 + sk]; \
    pb = *(const float4*)&W2[(size_t)(colBase + bc) * H_ + (IT) * 16 + bk];    \
  }

  K2_LOAD(0);
  for (int it = 0; it < 64; ++it) {
    if (it == 32) {  // chunk boundary k=512: join (tot was 0 -> exact)
#pragma unroll
      for (int i = 0; i < 2; ++i)
#pragma unroll
        for (int j = 0; j < 4; ++j)
#pragma unroll
          for (int tt = 0; tt < 4; ++tt) {
            tot[i][j][tt] += cur[i][j][tt];
            cur[i][j][tt] = 0.f;
          }
    }
    {
      unsigned b0 = pu & 0xFFu, b1v = (pu >> 8) & 0xFFu;
#pragma unroll
      for (int tt = 0; tt < 4; ++tt) {
        As[sk][sr * 4 + tt]     = (float)((b0 >> (tb + tt)) & 1u);
        As[sk + 1][sr * 4 + tt] = (float)((b1v >> (tb + tt)) & 1u);
      }
      Bs[bk + 0][bc] = pb.x; Bs[bk + 1][bc] = pb.y;
      Bs[bk + 2][bc] = pb.z; Bs[bk + 3][bc] = pb.w;
    }
    __syncthreads();
    if (it + 1 < 64) K2_LOAD(it + 1);   // hide global latency under compute
#pragma unroll
    for (int k = 0; k < 16; ++k) {
      float4 a0 = *(const float4*)&As[k][(ty * 2) * 4];
      float4 a1 = *(const float4*)&As[k][(ty * 2 + 1) * 4];
      float4 b  = *(const float4*)&Bs[k][tx * 4];
#pragma unroll
      for (int j = 0; j < 4; ++j)
#pragma unroll
        for (int tt = 0; tt < 4; ++tt) {
          cur[0][j][tt] = fmaf((&a0.x)[tt], (&b.x)[j], cur[0][j][tt]);
          cur[1][j][tt] = fmaf((&a1.x)[tt], (&b.x)[j], cur[1][j][tt]);
        }
    }
    __syncthreads();
  }
#undef K2_LOAD

  const int col0 = colBase + tx * 4;
  float4 b2v = *(const float4*)&B2[col0];
#pragma unroll
  for (int i = 0; i < 2; ++i) {
    int row = rowBase + ty * 2 + i;
    int bb = row >> 10;          // row / S_
    int ss = row & (S_ - 1);
    size_t slot4 = (((size_t)bb * T_ + 4) * S_ + ss) * O_ + col0;
    float mcur[4];
    if (tg == 0) {
      mcur[0] = 0.f; mcur[1] = 0.f; mcur[2] = 0.f; mcur[3] = 0.f;
    } else {
      float4 mp = *(const float4*)&out[slot4];  // stash from tg=0
      mcur[0] = mp.x; mcur[1] = mp.y; mcur[2] = mp.z; mcur[3] = mp.w;
    }
#pragma unroll
    for (int tt = 0; tt < 4; ++tt) {
      int t = tb + tt;
      float4 sp;
#pragma unroll
      for (int j = 0; j < 4; ++j) {
        float d = tot[i][j][tt] + cur[i][j][tt];   // ch0 + ch1
        float v = (mcur[j] + d) + (&b2v.x)[j];     // (mem2 + delta) + b2
        bool s = v > TH;
        (&sp.x)[j] = s ? 1.f : 0.f;
        mcur[j] = s ? 0.f : v;
      }
      *(float4*)&out[(((size_t)bb * T_ + t) * S_ + ss) * O_ + col0] = sp;
    }
    if (tg == 0) {
      float4 mn;
      mn.x = mcur[0]; mn.y = mcur[1]; mn.z = mcur[2]; mn.w = mcur[3];
      *(float4*)&out[slot4] = mn;   // stash; overwritten by tg=1's t=4 spikes
    }
  }
}

extern "C" void kernel_launch(void* const* d_in, const int* in_sizes, int n_in,
                              void* d_out, int out_size, void* d_ws, size_t ws_size,
                              hipStream_t stream) {
  const float* x  = (const float*)d_in[0];   // (B,S,I)
  const float* w1 = (const float*)d_in[1];   // (H,I)
  const float* b1 = (const float*)d_in[2];   // (H)
  const float* w2 = (const float*)d_in[3];   // (O,H)
  const float* b2 = (const float*)d_in[4];   // (O)
  float* out = (float*)d_out;                // (B,T,S,O) f32

  unsigned char* spikeB = (unsigned char*)d_ws;  // M*H bytes = 8.4 MB

  k1<<<dim3(M_ / 128, H_ / 64), 256, 0, stream>>>(x, w1, b1, spikeB);
  k2f<<<dim3(M_ / 32, O_ / 64), 256, 0, stream>>>(spikeB, w2, b2, out, 0);
  k2f<<<dim3(M_ / 32, O_ / 64), 256, 0, stream>>>(spikeB, w2, b2, out, 1);
}

// Round 28
// 825.218 us; speedup vs baseline: 1.2864x; 1.0209x over previous
//
#include <hip/hip_runtime.h>

// SNN layer: B=8, S=1024, I=512, H=1024, O=512, T=8
// Verified numerics (R22-R27 PASS, absmax=0): BLIS/AOCL kc=512 emulation:
//   K=512  -> single sequential ascending-k fused-FMA chain
//   K=1024 -> chains [0,512)+[512,1024), delta = ch0 + ch1 (one join add)
//   LIF: mem += c; spike = mem>0.5; fired -> 0.0. Layer2: (mem+delta)+b2.
// R28: k2 fuses ALL 8 timesteps in ONE launch. Thread = 1 row x 4 cols x 8 t
// (64 acc VGPR -> 4 waves/SIMD). mem2 recurrence entirely in registers; no
// state stash. Barriers/staging amortized 8x vs R26.
static constexpr int B_ = 8, S_ = 1024, I_ = 512, H_ = 1024, O_ = 512, T_ = 8;
static constexpr int M_ = B_ * S_;
static constexpr float TH = 0.5f;

// ---------------------------------------------------------------------------
// K1 (unchanged R26): inp_cur = dot(x, w1^T) + b1 (full-K single chain) ->
// 8-step LIF -> bit-packed spikes. 128x64 tile, 8x4/thread, BK=16.
// ---------------------------------------------------------------------------
__global__ __launch_bounds__(256) void k1(const float* __restrict__ X,
                                          const float* __restrict__ W1,
                                          const float* __restrict__ B1,
                                          unsigned char* __restrict__ SPB) {
  __shared__ float As[16][132];
  __shared__ float Bs[16][68];
  const int tid = threadIdx.x;
  const int tx = tid & 15, ty = tid >> 4;
  const int rowBase = blockIdx.x * 128, colBase = blockIdx.y * 64;
  const int rrA = tid >> 2, kqA = (tid & 3) << 2;

  float acc[8][4];
#pragma unroll
  for (int i = 0; i < 8; ++i)
#pragma unroll
    for (int j = 0; j < 4; ++j) acc[i][j] = 0.f;

  float4 pa0, pa1, pb;
#define K1_LOAD(IT)                                                            \
  {                                                                            \
    pa0 = *(const float4*)&X[(size_t)(rowBase + rrA) * I_ + (IT) * 16 + kqA];  \
    pa1 = *(const float4*)&X[(size_t)(rowBase + 64 + rrA) * I_ + (IT) * 16 + kqA]; \
    pb  = *(const float4*)&W1[(size_t)(colBase + rrA) * I_ + (IT) * 16 + kqA]; \
  }

  K1_LOAD(0);
  for (int it = 0; it < 32; ++it) {
    As[kqA + 0][rrA] = pa0.x; As[kqA + 1][rrA] = pa0.y;
    As[kqA + 2][rrA] = pa0.z; As[kqA + 3][rrA] = pa0.w;
    As[kqA + 0][64 + rrA] = pa1.x; As[kqA + 1][64 + rrA] = pa1.y;
    As[kqA + 2][64 + rrA] = pa1.z; As[kqA + 3][64 + rrA] = pa1.w;
    Bs[kqA + 0][rrA] = pb.x; Bs[kqA + 1][rrA] = pb.y;
    Bs[kqA + 2][rrA] = pb.z; Bs[kqA + 3][rrA] = pb.w;
    __syncthreads();
    if (it + 1 < 32) K1_LOAD(it + 1);
#pragma unroll
    for (int k = 0; k < 16; ++k) {
      float a[8], b[4];
      *(float4*)&a[0] = *(const float4*)&As[k][ty * 8];
      *(float4*)&a[4] = *(const float4*)&As[k][ty * 8 + 4];
      *(float4*)&b[0] = *(const float4*)&Bs[k][tx * 4];
#pragma unroll
      for (int i = 0; i < 8; ++i)
#pragma unroll
        for (int j = 0; j < 4; ++j) acc[i][j] = fmaf(a[i], b[j], acc[i][j]);
    }
    __syncthreads();
  }
#undef K1_LOAD

#pragma unroll
  for (int i = 0; i < 8; ++i) {
    int row = rowBase + ty * 8 + i;
    unsigned char by[4];
#pragma unroll
    for (int j = 0; j < 4; ++j) {
      int col = colBase + tx * 4 + j;
      float c = acc[i][j] + B1[col];
      float m = 0.f;
      unsigned bits = 0;
#pragma unroll
      for (int t = 0; t < 8; ++t) {
        m = m + c;
        bool s = m > TH;
        bits |= (s ? 1u : 0u) << t;
        m = s ? 0.f : m;
      }
      by[j] = (unsigned char)bits;
    }
    uchar4 pk; pk.x = by[0]; pk.y = by[1]; pk.z = by[2]; pk.w = by[3];
    *(uchar4*)&SPB[(size_t)row * H_ + colBase + tx * 4] = pk;
  }
}

// ---------------------------------------------------------------------------
// K2F8: all 8 timesteps in one launch. Block 16 rows x 64 cols, 256 threads.
// Thread: 1 row (ty), 4 cols (tx*4), 8 t. As[k][row*8+t] spike floats;
// Bs[k][col] = W2. Chunk join at it==32 (k=512): tot += cur (tot=0 exact).
// Epilogue: full 8-step mem2 recurrence in registers; spikes written direct.
// ---------------------------------------------------------------------------
__global__ __launch_bounds__(256) void k2f8(const unsigned char* __restrict__ SP,
                                            const float* __restrict__ W2,
                                            const float* __restrict__ B2,
                                            float* __restrict__ out) {
  __shared__ float As[16][132];   // [k][row*8 + t], 16 rows x 8t (+4 pad)
  __shared__ float Bs[16][68];    // [k][col], 64 cols
  const int tid = threadIdx.x;
  const int tx = tid & 15, ty = tid >> 4;   // ty = row 0..15
  const int rowBase = blockIdx.x * 16, colBase = blockIdx.y * 64;
  const int srow = tid & 15, sk = tid >> 4;  // A staging: 16 rows x 16 k bytes
  const int bc = tid >> 2, bk = (tid & 3) << 2;  // B staging

  float tot[4][8], cur[4][8];    // [j(col)][t]
#pragma unroll
  for (int j = 0; j < 4; ++j)
#pragma unroll
    for (int t = 0; t < 8; ++t) { tot[j][t] = 0.f; cur[j][t] = 0.f; }

  unsigned char pu;
  float4 pb;
#define K2_LOAD(IT)                                                            \
  {                                                                            \
    pu = SP[(size_t)(rowBase + srow) * H_ + (IT) * 16 + sk];                   \
    pb = *(const float4*)&W2[(size_t)(colBase + bc) * H_ + (IT) * 16 + bk];    \
  }

  K2_LOAD(0);
  for (int it = 0; it < 64; ++it) {
    if (it == 32) {  // chunk boundary k=512: join (tot was 0 -> exact)
#pragma unroll
      for (int j = 0; j < 4; ++j)
#pragma unroll
        for (int t = 0; t < 8; ++t) { tot[j][t] += cur[j][t]; cur[j][t] = 0.f; }
    }
    {
#pragma unroll
      for (int t = 0; t < 8; ++t)
        As[sk][srow * 8 + t] = (float)((pu >> t) & 1u);
      Bs[bk + 0][bc] = pb.x; Bs[bk + 1][bc] = pb.y;
      Bs[bk + 2][bc] = pb.z; Bs[bk + 3][bc] = pb.w;
    }
    __syncthreads();
    if (it + 1 < 64) K2_LOAD(it + 1);   // hide global latency under compute
#pragma unroll
    for (int k = 0; k < 16; ++k) {
      float a[8], b[4];
      *(float4*)&a[0] = *(const float4*)&As[k][ty * 8];
      *(float4*)&a[4] = *(const float4*)&As[k][ty * 8 + 4];
      *(float4*)&b[0] = *(const float4*)&Bs[k][tx * 4];
#pragma unroll
      for (int j = 0; j < 4; ++j)
#pragma unroll
        for (int t = 0; t < 8; ++t)
          cur[j][t] = fmaf(a[t], b[j], cur[j][t]);
    }
    __syncthreads();
  }
#undef K2_LOAD

  const int col0 = colBase + tx * 4;
  float4 b2v = *(const float4*)&B2[col0];
  const int row = rowBase + ty;
  const int bb = row >> 10;          // row / S_
  const int ss = row & (S_ - 1);
  float m[4] = {0.f, 0.f, 0.f, 0.f};
#pragma unroll
  for (int t = 0; t < 8; ++t) {
    float4 sp;
#pragma unroll
    for (int j = 0; j < 4; ++j) {
      float d = tot[j][t] + cur[j][t];       // ch0 + ch1 (single join add)
      float v = (m[j] + d) + (&b2v.x)[j];    // (mem2 + delta) + b2
      bool s = v > TH;
      (&sp.x)[j] = s ? 1.f : 0.f;
      m[j] = s ? 0.f : v;
    }
    *(float4*)&out[(((size_t)bb * T_ + t) * S_ + ss) * O_ + col0] = sp;
  }
}

extern "C" void kernel_launch(void* const* d_in, const int* in_sizes, int n_in,
                              void* d_out, int out_size, void* d_ws, size_t ws_size,
                              hipStream_t stream) {
  const float* x  = (const float*)d_in[0];   // (B,S,I)
  const float* w1 = (const float*)d_in[1];   // (H,I)
  const float* b1 = (const float*)d_in[2];   // (H)
  const float* w2 = (const float*)d_in[3];   // (O,H)
  const float* b2 = (const float*)d_in[4];   // (O)
  float* out = (float*)d_out;                // (B,T,S,O) f32

  unsigned char* spikeB = (unsigned char*)d_ws;  // M*H bytes = 8.4 MB

  k1<<<dim3(M_ / 128, H_ / 64), 256, 0, stream>>>(x, w1, b1, spikeB);
  k2f8<<<dim3(M_ / 16, O_ / 64), 256, 0, stream>>>(spikeB, w2, b2, out);
}